// Round 11
// baseline (928.205 us; speedup 1.0000x reference)
//
#include <hip/hip_runtime.h>

#define NODE_DIM 256
#define HIDDEN 64
#define NUM_REL 10

#define FMA4(A, S, W) do { \
    (A).x = fmaf((S), (W).x, (A).x); \
    (A).y = fmaf((S), (W).y, (A).y); \
    (A).z = fmaf((S), (W).z, (A).z); \
    (A).w = fmaf((S), (W).w, (A).w); } while (0)

#define ELEM(V, I) ((I) == 0 ? (V).x : (I) == 1 ? (V).y : (I) == 2 ? (V).z : (V).w)

// ---- node kernel: round-5 version verbatim (~105 us; wave-uniform W rows ->
// s_load scalarization; thread-per-node). np/BLAS rounding order: acc=0,
// ascending-k fmaf chain, bias added AFTER as separate add, then relu.
//   h1 = relu((x@W1)+b1); h = (h1@W2)+b2 -> stored; A = h@W3[0:64] -> stored.
__global__ __launch_bounds__(256) void node_kernel(
    const float* __restrict__ x,
    const float* __restrict__ W1, const float* __restrict__ b1,
    const float* __restrict__ W2, const float* __restrict__ b2,
    const float* __restrict__ W3,
    float* __restrict__ Hout, float* __restrict__ Aout, int N)
{
    int n = blockIdx.x * 256 + threadIdx.x;
    if (n >= N) return;

    // ---- L1: h1 = relu((x@W1) + b1) ----
    float h1[64];
    #pragma unroll
    for (int j = 0; j < 64; ++j) h1[j] = 0.0f;

    const float4* xr = (const float4*)(x + (size_t)n * NODE_DIM);
    #pragma unroll 1
    for (int k4 = 0; k4 < NODE_DIM / 4; ++k4) {
        float4 xv = xr[k4];
        const float* w = W1 + (size_t)k4 * 4 * 64;
        #pragma unroll
        for (int j = 0; j < 64; ++j) h1[j] = fmaf(xv.x, w[j], h1[j]);
        #pragma unroll
        for (int j = 0; j < 64; ++j) h1[j] = fmaf(xv.y, w[64 + j], h1[j]);
        #pragma unroll
        for (int j = 0; j < 64; ++j) h1[j] = fmaf(xv.z, w[128 + j], h1[j]);
        #pragma unroll
        for (int j = 0; j < 64; ++j) h1[j] = fmaf(xv.w, w[192 + j], h1[j]);
    }
    #pragma unroll
    for (int j = 0; j < 64; ++j) h1[j] = fmaxf(h1[j] + b1[j], 0.0f);

    // ---- L2: h = (h1@W2) + b2 ----
    float h[64];
    #pragma unroll
    for (int c = 0; c < 4; ++c) {
        float acc[16];
        #pragma unroll
        for (int j = 0; j < 16; ++j) acc[j] = 0.0f;
        #pragma unroll
        for (int k = 0; k < 64; ++k) {
            const float* w = W2 + (size_t)k * 64 + c * 16;
            #pragma unroll
            for (int j = 0; j < 16; ++j) acc[j] = fmaf(h1[k], w[j], acc[j]);
        }
        #pragma unroll
        for (int j = 0; j < 16; ++j) h[c * 16 + j] = acc[j] + b2[c * 16 + j];
    }

    float4* hr = (float4*)(Hout + (size_t)n * 64);
    #pragma unroll
    for (int j4 = 0; j4 < 16; ++j4) {
        float4 v;
        v.x = h[4 * j4]; v.y = h[4 * j4 + 1];
        v.z = h[4 * j4 + 2]; v.w = h[4 * j4 + 3];
        hr[j4] = v;
    }

    // ---- L3 row-half partial: A = h @ W3[0:64], no bias ----
    float4* ar = (float4*)(Aout + (size_t)n * 64);
    #pragma unroll
    for (int c = 0; c < 4; ++c) {
        float acc[16];
        #pragma unroll
        for (int j = 0; j < 16; ++j) acc[j] = 0.0f;
        #pragma unroll
        for (int k = 0; k < 64; ++k) {
            const float* w = W3 + (size_t)k * 64 + c * 16;
            #pragma unroll
            for (int j = 0; j < 16; ++j) acc[j] = fmaf(h[k], w[j], acc[j]);
        }
        #pragma unroll
        for (int j4 = 0; j4 < 4; ++j4) {
            float4 v;
            v.x = acc[4 * j4]; v.y = acc[4 * j4 + 1];
            v.z = acc[4 * j4 + 2]; v.w = acc[4 * j4 + 3];
            ar[c * 4 + j4] = v;
        }
    }
}

// Edge kernel: block = 4 waves = 128 edges. Hc rows staged ONCE in LDS
// (quad-swizzled for even bank use); wave pair {2p, 2p+1} handles j-halves
// {0,1} of edges p*64+lane. Each wave: seed acc from its 128B half of A[row],
// k-chain (W3 rows 64..127 ascending, wave-uniform weight s_loads), +b3,
// relu. Logit chain in np order: even wave j=0..31 -> LDS, odd wave CONTINUES
// the same fmaf chain j=32..63, +b4, argmax, softmax, store. Bit-identical
// rounding per output element. ~55 live VGPRs by construction.
__global__ __launch_bounds__(256) void edge_kernel(
    const int* __restrict__ ei,
    const float* __restrict__ H, const float* __restrict__ A,
    const float* __restrict__ W3, const float* __restrict__ b3,
    const float* __restrict__ W4, const float* __restrict__ b4,
    float* __restrict__ out_type, float* __restrict__ out_probs, int E)
{
    __shared__ float HcS[128][64];
    __shared__ float lgS[128][11];   // stride 11: gcd(11,32)=1, even banks

    const int tid = threadIdx.x;
    const int ebase = blockIdx.x * 128;

    // ---- stage Hc: thread t loads row t/2, half t&1 (full 64B lines) ----
    {
        const int row = tid >> 1;
        const int hs  = tid & 1;
        const int es  = ebase + row;
        if (es < E) {
            const int c = ei[E + es];
            const float4* src = (const float4*)(H + (size_t)c * 64) + hs * 8;
            #pragma unroll
            for (int i = 0; i < 8; ++i) {
                const int q = hs * 8 + i;
                *(float4*)&HcS[row][((q + row) & 15) * 4] = src[i];
            }
        }
    }
    __syncthreads();

    const int w    = tid >> 6;          // wave 0..3
    const int lane = tid & 63;
    const int half = w & 1;             // j-half this wave owns
    const int el   = (w >> 1) * 64 + lane;   // edge slot 0..127
    const int e    = ebase + el;
    const bool valid = (e < E);

    // seed from A[row] chain prefix (this wave's 128B half)
    float4 acc[8];
    {
        const int r = valid ? ei[e] : 0;
        const float4* Ar = (const float4*)(A + (size_t)r * 64) + half * 8;
        #pragma unroll
        for (int j = 0; j < 8; ++j) acc[j] = Ar[j];
    }

    // k-chain: W3 rows 64..127 ascending, hc from LDS (swizzled quads)
    const float* W3h = W3 + 64 * 64 + half * 32;
    #pragma unroll 1
    for (int k4 = 0; k4 < 16; ++k4) {
        const float4 hv = *(const float4*)&HcS[el][((k4 + el) & 15) * 4];
        #pragma unroll
        for (int i = 0; i < 4; ++i) {
            const float s = ELEM(hv, i);
            const float* wp = W3h + (size_t)(k4 * 4 + i) * 64;
            #pragma unroll
            for (int j = 0; j < 8; ++j) {
                float4 wv = *(const float4*)(wp + 4 * j);
                FMA4(acc[j], s, wv);
            }
        }
    }

    // + b3 (half slice), relu
    const float* b3h = b3 + half * 32;
    #pragma unroll
    for (int j = 0; j < 8; ++j) {
        float4 bv = *(const float4*)(b3h + 4 * j);
        acc[j].x = fmaxf(acc[j].x + bv.x, 0.f);
        acc[j].y = fmaxf(acc[j].y + bv.y, 0.f);
        acc[j].z = fmaxf(acc[j].z + bv.z, 0.f);
        acc[j].w = fmaxf(acc[j].w + bv.w, 0.f);
    }

    // ---- logits, np chain order over j ascending ----
    if (half == 0) {                    // wave-uniform branch, no divergence
        float lg[NUM_REL];
        #pragma unroll
        for (int j = 0; j < NUM_REL; ++j) lg[j] = 0.0f;
        #pragma unroll
        for (int jq = 0; jq < 8; ++jq) {
            #pragma unroll
            for (int i = 0; i < 4; ++i) {
                const float s = ELEM(acc[jq], i);
                const float* wp = W4 + (size_t)(jq * 4 + i) * NUM_REL;
                #pragma unroll
                for (int j = 0; j < NUM_REL; ++j) lg[j] = fmaf(s, wp[j], lg[j]);
            }
        }
        #pragma unroll
        for (int j = 0; j < NUM_REL; ++j) lgS[el][j] = lg[j];
    }
    __syncthreads();
    if (half == 1) {
        float lg[NUM_REL];
        #pragma unroll
        for (int j = 0; j < NUM_REL; ++j) lg[j] = lgS[el][j];
        #pragma unroll
        for (int jq = 0; jq < 8; ++jq) {
            #pragma unroll
            for (int i = 0; i < 4; ++i) {
                const float s = ELEM(acc[jq], i);
                const float* wp = W4 + (size_t)(32 + jq * 4 + i) * NUM_REL;
                #pragma unroll
                for (int j = 0; j < NUM_REL; ++j) lg[j] = fmaf(s, wp[j], lg[j]);
            }
        }
        #pragma unroll
        for (int j = 0; j < NUM_REL; ++j) lg[j] += b4[j];

        // argmax, first occurrence
        int best = 0;
        float bm = lg[0];
        #pragma unroll
        for (int j = 1; j < NUM_REL; ++j)
            if (lg[j] > bm) { bm = lg[j]; best = j; }

        // softmax fp32
        float p[NUM_REL];
        float sum = 0.0f;
        #pragma unroll
        for (int j = 0; j < NUM_REL; ++j) {
            p[j] = expf(lg[j] - bm);
            sum += p[j];
        }
        float inv = 1.0f / sum;

        if (valid) {
            out_type[e] = (float)best;
            float* op = out_probs + (size_t)e * NUM_REL;
            #pragma unroll
            for (int j = 0; j < NUM_REL; ++j) op[j] = p[j] * inv;
        }
    }
}

extern "C" void kernel_launch(void* const* d_in, const int* in_sizes, int n_in,
                              void* d_out, int out_size, void* d_ws, size_t ws_size,
                              hipStream_t stream)
{
    const float* x  = (const float*)d_in[0];
    const int*   ei = (const int*)d_in[1];
    const float* W1 = (const float*)d_in[2];
    const float* b1 = (const float*)d_in[3];
    const float* W2 = (const float*)d_in[4];
    const float* b2 = (const float*)d_in[5];
    const float* W3 = (const float*)d_in[6];
    const float* b3 = (const float*)d_in[7];
    const float* W4 = (const float*)d_in[8];
    const float* b4 = (const float*)d_in[9];

    int N = in_sizes[0] / NODE_DIM;   // 100000
    int E = in_sizes[1] / 2;          // 1600000

    // ws: H [N*64] f32 | A [N*64] f32   (51.2 MB total)
    float* H = (float*)d_ws;
    float* A = H + (size_t)N * 64;

    int nb = (N + 255) / 256;
    int eb = (E + 127) / 128;

    float* out_type  = (float*)d_out;
    float* out_probs = (float*)d_out + E;

    hipLaunchKernelGGL(node_kernel, dim3(nb), dim3(256), 0, stream,
                       x, W1, b1, W2, b2, W3, H, A, N);
    hipLaunchKernelGGL(edge_kernel, dim3(eb), dim3(256), 0, stream,
                       ei, H, A, W3, b3, W4, b4, out_type, out_probs, E);
}

// Round 12
// 556.684 us; speedup vs baseline: 1.6674x; 1.6674x over previous
//
#include <hip/hip_runtime.h>

#define NODE_DIM 256
#define HIDDEN 64
#define NUM_REL 10

#define FMA4(A, S, W) do { \
    (A).x = fmaf((S), (W).x, (A).x); \
    (A).y = fmaf((S), (W).y, (A).y); \
    (A).z = fmaf((S), (W).z, (A).z); \
    (A).w = fmaf((S), (W).w, (A).w); } while (0)

#define ELEM(V, I) ((I) == 0 ? (V).x : (I) == 1 ? (V).y : (I) == 2 ? (V).z : (V).w)

// ---- node kernel: round-5 version verbatim (~105 us; wave-uniform W rows ->
// s_load scalarization; thread-per-node). np/BLAS rounding order: acc=0,
// ascending-k fmaf chain, bias added AFTER as separate add, then relu.
//   h1 = relu((x@W1)+b1); h = (h1@W2)+b2 -> stored; A = h@W3[0:64] -> stored.
__global__ __launch_bounds__(256) void node_kernel(
    const float* __restrict__ x,
    const float* __restrict__ W1, const float* __restrict__ b1,
    const float* __restrict__ W2, const float* __restrict__ b2,
    const float* __restrict__ W3,
    float* __restrict__ Hout, float* __restrict__ Aout, int N)
{
    int n = blockIdx.x * 256 + threadIdx.x;
    if (n >= N) return;

    // ---- L1: h1 = relu((x@W1) + b1) ----
    float h1[64];
    #pragma unroll
    for (int j = 0; j < 64; ++j) h1[j] = 0.0f;

    const float4* xr = (const float4*)(x + (size_t)n * NODE_DIM);
    #pragma unroll 1
    for (int k4 = 0; k4 < NODE_DIM / 4; ++k4) {
        float4 xv = xr[k4];
        const float* w = W1 + (size_t)k4 * 4 * 64;
        #pragma unroll
        for (int j = 0; j < 64; ++j) h1[j] = fmaf(xv.x, w[j], h1[j]);
        #pragma unroll
        for (int j = 0; j < 64; ++j) h1[j] = fmaf(xv.y, w[64 + j], h1[j]);
        #pragma unroll
        for (int j = 0; j < 64; ++j) h1[j] = fmaf(xv.z, w[128 + j], h1[j]);
        #pragma unroll
        for (int j = 0; j < 64; ++j) h1[j] = fmaf(xv.w, w[192 + j], h1[j]);
    }
    #pragma unroll
    for (int j = 0; j < 64; ++j) h1[j] = fmaxf(h1[j] + b1[j], 0.0f);

    // ---- L2: h = (h1@W2) + b2 ----
    float h[64];
    #pragma unroll
    for (int c = 0; c < 4; ++c) {
        float acc[16];
        #pragma unroll
        for (int j = 0; j < 16; ++j) acc[j] = 0.0f;
        #pragma unroll
        for (int k = 0; k < 64; ++k) {
            const float* w = W2 + (size_t)k * 64 + c * 16;
            #pragma unroll
            for (int j = 0; j < 16; ++j) acc[j] = fmaf(h1[k], w[j], acc[j]);
        }
        #pragma unroll
        for (int j = 0; j < 16; ++j) h[c * 16 + j] = acc[j] + b2[c * 16 + j];
    }

    float4* hr = (float4*)(Hout + (size_t)n * 64);
    #pragma unroll
    for (int j4 = 0; j4 < 16; ++j4) {
        float4 v;
        v.x = h[4 * j4]; v.y = h[4 * j4 + 1];
        v.z = h[4 * j4 + 2]; v.w = h[4 * j4 + 3];
        hr[j4] = v;
    }

    // ---- L3 row-half partial: A = h @ W3[0:64], no bias ----
    float4* ar = (float4*)(Aout + (size_t)n * 64);
    #pragma unroll
    for (int c = 0; c < 4; ++c) {
        float acc[16];
        #pragma unroll
        for (int j = 0; j < 16; ++j) acc[j] = 0.0f;
        #pragma unroll
        for (int k = 0; k < 64; ++k) {
            const float* w = W3 + (size_t)k * 64 + c * 16;
            #pragma unroll
            for (int j = 0; j < 16; ++j) acc[j] = fmaf(h[k], w[j], acc[j]);
        }
        #pragma unroll
        for (int j4 = 0; j4 < 4; ++j4) {
            float4 v;
            v.x = acc[4 * j4]; v.y = acc[4 * j4 + 1];
            v.z = acc[4 * j4 + 2]; v.w = acc[4 * j4 + 3];
            ar[c * 4 + j4] = v;
        }
    }
}

// Edge kernel = round-10 compute structure (per-thread j-half split, ~44 VGPR,
// in-thread np-ordered logit chain) + ONE-SHOT LDS staging of Hc rows.
// Each 256-thread block stages its 256 H[col] rows into LDS (64 KB) with an
// XOR-quad swizzle (bijective per row, spreads banks at the 1024B/instr
// floor); both j-halves then consume Hc from LDS. Chain order per output
// element unchanged -> bit-identical to np.
__global__ __launch_bounds__(256) void edge_kernel(
    const int* __restrict__ ei,
    const float* __restrict__ H, const float* __restrict__ A,
    const float* __restrict__ W3, const float* __restrict__ b3,
    const float* __restrict__ W4, const float* __restrict__ b4,
    float* __restrict__ out_type, float* __restrict__ out_probs, int E)
{
    __shared__ float4 HcS[256 * 16];   // [row][quad], quad XOR-swizzled: 64 KB

    const int tid = threadIdx.x;
    const int e = blockIdx.x * 256 + tid;
    const bool valid = (e < E);
    const int sw = tid & 15;

    // ---- stage own edge's Hc row (16 float4, vmcnt-pipelined) ----
    {
        const int c = valid ? ei[E + e] : 0;
        const float4* src = (const float4*)(H + (size_t)c * 64);
        #pragma unroll
        for (int q = 0; q < 16; ++q)
            HcS[tid * 16 + (q ^ sw)] = src[q];
    }
    __syncthreads();

    const int r = valid ? ei[e] : 0;
    const float4* Ar = (const float4*)(A + (size_t)r * 64);
    const float* W3b = W3 + 64 * 64;
    const float4* hrow = &HcS[tid * 16];

    float lg[NUM_REL];
    #pragma unroll
    for (int j = 0; j < NUM_REL; ++j) lg[j] = 0.0f;

    #pragma unroll
    for (int half = 0; half < 2; ++half) {      // fully unrolled: static indices
        // seed this half's 8 accumulators from the A chain prefix
        float4 acc[8];
        #pragma unroll
        for (int j = 0; j < 8; ++j) acc[j] = Ar[half * 8 + j];

        // k-chain: W3 rows 64..127 ascending, hc from LDS (swizzled quads)
        #pragma unroll 1
        for (int k4 = 0; k4 < 16; ++k4) {
            const float4 hv = hrow[k4 ^ sw];
            #pragma unroll
            for (int i = 0; i < 4; ++i) {
                const float s = ELEM(hv, i);
                const float* w = W3b + (size_t)(k4 * 4 + i) * 64 + half * 32;
                #pragma unroll
                for (int j = 0; j < 8; ++j) {
                    float4 wv = *(const float4*)(w + 4 * j);
                    FMA4(acc[j], s, wv);
                }
            }
        }

        // + b3, relu (this half's slice)
        #pragma unroll
        for (int j = 0; j < 8; ++j) {
            float4 bv = *(const float4*)(b3 + half * 32 + 4 * j);
            acc[j].x = fmaxf(acc[j].x + bv.x, 0.f);
            acc[j].y = fmaxf(acc[j].y + bv.y, 0.f);
            acc[j].z = fmaxf(acc[j].z + bv.z, 0.f);
            acc[j].w = fmaxf(acc[j].w + bv.w, 0.f);
        }

        // logits: continue lg chain over this half's j-range, ascending
        #pragma unroll
        for (int jq = 0; jq < 8; ++jq) {
            #pragma unroll
            for (int i = 0; i < 4; ++i) {
                const float s = ELEM(acc[jq], i);
                const float* w = W4 + (size_t)(half * 32 + jq * 4 + i) * NUM_REL;
                #pragma unroll
                for (int j = 0; j < NUM_REL; ++j) lg[j] = fmaf(s, w[j], lg[j]);
            }
        }
    }

    if (!valid) return;

    #pragma unroll
    for (int j = 0; j < NUM_REL; ++j) lg[j] += b4[j];

    // argmax, first occurrence
    int best = 0;
    float bm = lg[0];
    #pragma unroll
    for (int j = 1; j < NUM_REL; ++j)
        if (lg[j] > bm) { bm = lg[j]; best = j; }

    // softmax fp32
    float p[NUM_REL];
    float sum = 0.0f;
    #pragma unroll
    for (int j = 0; j < NUM_REL; ++j) {
        p[j] = expf(lg[j] - bm);
        sum += p[j];
    }
    float inv = 1.0f / sum;

    out_type[e] = (float)best;
    float* op = out_probs + (size_t)e * NUM_REL;
    #pragma unroll
    for (int j = 0; j < NUM_REL; ++j) op[j] = p[j] * inv;
}

extern "C" void kernel_launch(void* const* d_in, const int* in_sizes, int n_in,
                              void* d_out, int out_size, void* d_ws, size_t ws_size,
                              hipStream_t stream)
{
    const float* x  = (const float*)d_in[0];
    const int*   ei = (const int*)d_in[1];
    const float* W1 = (const float*)d_in[2];
    const float* b1 = (const float*)d_in[3];
    const float* W2 = (const float*)d_in[4];
    const float* b2 = (const float*)d_in[5];
    const float* W3 = (const float*)d_in[6];
    const float* b3 = (const float*)d_in[7];
    const float* W4 = (const float*)d_in[8];
    const float* b4 = (const float*)d_in[9];

    int N = in_sizes[0] / NODE_DIM;   // 100000
    int E = in_sizes[1] / 2;          // 1600000

    // ws: H [N*64] f32 | A [N*64] f32   (51.2 MB total)
    float* H = (float*)d_ws;
    float* A = H + (size_t)N * 64;

    int nb = (N + 255) / 256;
    int eb = (E + 255) / 256;

    float* out_type  = (float*)d_out;
    float* out_probs = (float*)d_out + E;

    hipLaunchKernelGGL(node_kernel, dim3(nb), dim3(256), 0, stream,
                       x, W1, b1, W2, b2, W3, H, A, N);
    hipLaunchKernelGGL(edge_kernel, dim3(eb), dim3(256), 0, stream,
                       ei, H, A, W3, b3, W4, b4, out_type, out_probs, E);
}

// Round 13
// 323.760 us; speedup vs baseline: 2.8670x; 1.7194x over previous
//
#include <hip/hip_runtime.h>

#define NODE_DIM 256
#define HIDDEN 64
#define NUM_REL 10

#define FMA4(A, S, W) do { \
    (A).x = fmaf((S), (W).x, (A).x); \
    (A).y = fmaf((S), (W).y, (A).y); \
    (A).z = fmaf((S), (W).z, (A).z); \
    (A).w = fmaf((S), (W).w, (A).w); } while (0)

#define ELEM(V, I) ((I) == 0 ? (V).x : (I) == 1 ? (V).y : (I) == 2 ? (V).z : (V).w)

// ---- node kernel: round-5 version verbatim (~105 us; wave-uniform W rows ->
// s_load scalarization; thread-per-node). np/BLAS rounding order: acc=0,
// ascending-k fmaf chain, bias added AFTER as separate add, then relu.
//   h1 = relu((x@W1)+b1); h = (h1@W2)+b2 -> stored; A = h@W3[0:64] -> stored.
__global__ __launch_bounds__(256) void node_kernel(
    const float* __restrict__ x,
    const float* __restrict__ W1, const float* __restrict__ b1,
    const float* __restrict__ W2, const float* __restrict__ b2,
    const float* __restrict__ W3,
    float* __restrict__ Hout, float* __restrict__ Aout, int N)
{
    int n = blockIdx.x * 256 + threadIdx.x;
    if (n >= N) return;

    // ---- L1: h1 = relu((x@W1) + b1) ----
    float h1[64];
    #pragma unroll
    for (int j = 0; j < 64; ++j) h1[j] = 0.0f;

    const float4* xr = (const float4*)(x + (size_t)n * NODE_DIM);
    #pragma unroll 1
    for (int k4 = 0; k4 < NODE_DIM / 4; ++k4) {
        float4 xv = xr[k4];
        const float* w = W1 + (size_t)k4 * 4 * 64;
        #pragma unroll
        for (int j = 0; j < 64; ++j) h1[j] = fmaf(xv.x, w[j], h1[j]);
        #pragma unroll
        for (int j = 0; j < 64; ++j) h1[j] = fmaf(xv.y, w[64 + j], h1[j]);
        #pragma unroll
        for (int j = 0; j < 64; ++j) h1[j] = fmaf(xv.z, w[128 + j], h1[j]);
        #pragma unroll
        for (int j = 0; j < 64; ++j) h1[j] = fmaf(xv.w, w[192 + j], h1[j]);
    }
    #pragma unroll
    for (int j = 0; j < 64; ++j) h1[j] = fmaxf(h1[j] + b1[j], 0.0f);

    // ---- L2: h = (h1@W2) + b2 ----
    float h[64];
    #pragma unroll
    for (int c = 0; c < 4; ++c) {
        float acc[16];
        #pragma unroll
        for (int j = 0; j < 16; ++j) acc[j] = 0.0f;
        #pragma unroll
        for (int k = 0; k < 64; ++k) {
            const float* w = W2 + (size_t)k * 64 + c * 16;
            #pragma unroll
            for (int j = 0; j < 16; ++j) acc[j] = fmaf(h1[k], w[j], acc[j]);
        }
        #pragma unroll
        for (int j = 0; j < 16; ++j) h[c * 16 + j] = acc[j] + b2[c * 16 + j];
    }

    float4* hr = (float4*)(Hout + (size_t)n * 64);
    #pragma unroll
    for (int j4 = 0; j4 < 16; ++j4) {
        float4 v;
        v.x = h[4 * j4]; v.y = h[4 * j4 + 1];
        v.z = h[4 * j4 + 2]; v.w = h[4 * j4 + 3];
        hr[j4] = v;
    }

    // ---- L3 row-half partial: A = h @ W3[0:64], no bias ----
    float4* ar = (float4*)(Aout + (size_t)n * 64);
    #pragma unroll
    for (int c = 0; c < 4; ++c) {
        float acc[16];
        #pragma unroll
        for (int j = 0; j < 16; ++j) acc[j] = 0.0f;
        #pragma unroll
        for (int k = 0; k < 64; ++k) {
            const float* w = W3 + (size_t)k * 64 + c * 16;
            #pragma unroll
            for (int j = 0; j < 16; ++j) acc[j] = fmaf(h[k], w[j], acc[j]);
        }
        #pragma unroll
        for (int j4 = 0; j4 < 4; ++j4) {
            float4 v;
            v.x = acc[4 * j4]; v.y = acc[4 * j4 + 1];
            v.z = acc[4 * j4 + 2]; v.w = acc[4 * j4 + 3];
            ar[c * 4 + j4] = v;
        }
    }
}

// Edge kernel: per-thread LDS scratch (32 KB/block -> 4 blocks/CU), Hc row
// staged in TWO chunks of 8 quads (each 128B L2 line still fetched exactly
// once; no __syncthreads — threads touch only their own scratch row).
// All 16 acc quads live through an unroll-1 k-loop (accumulators can't be
// rematerialized -> no strip-mining), seeded from A[row] chain prefix.
// Chain order per output element: k ascending over W3 rows 64..127, +b3,
// relu, logits over j ascending, +b4 — bit-identical to np.
__global__ __launch_bounds__(256, 4) void edge_kernel(
    const int* __restrict__ ei,
    const float* __restrict__ H, const float* __restrict__ A,
    const float* __restrict__ W3, const float* __restrict__ b3,
    const float* __restrict__ W4, const float* __restrict__ b4,
    float* __restrict__ out_type, float* __restrict__ out_probs, int E)
{
    __shared__ float4 HcS[256 * 8];   // 32 KB: per-thread 8-quad scratch

    const int tid = threadIdx.x;
    const int e = blockIdx.x * 256 + tid;
    const bool valid = (e < E);
    const int sw = tid & 7;           // XOR swizzle: even bank use on b128 ops
    float4* myscr = &HcS[tid * 8];

    const int c = valid ? ei[E + e] : 0;
    const int r = valid ? ei[e] : 0;
    const float4* src = (const float4*)(H + (size_t)c * 64);
    const float4* Ar  = (const float4*)(A + (size_t)r * 64);

    // stage chunk 0: Hc quads 0..7
    #pragma unroll
    for (int q = 0; q < 8; ++q) myscr[q ^ sw] = src[q];

    // seed all 16 acc quads from the A chain prefix
    float4 acc[16];
    #pragma unroll
    for (int j = 0; j < 16; ++j) acc[j] = Ar[j];

    const float* W3b = W3 + 64 * 64;

    // chunk 0: k4 = 0..7 (W3 rows 64..95, ascending)
    #pragma unroll 1
    for (int k4 = 0; k4 < 8; ++k4) {
        const float4 hv = myscr[k4 ^ sw];
        #pragma unroll
        for (int i = 0; i < 4; ++i) {
            const float s = ELEM(hv, i);
            const float* w = W3b + (size_t)(k4 * 4 + i) * 64;
            #pragma unroll
            for (int j = 0; j < 16; ++j) {
                float4 wv = *(const float4*)(w + 4 * j);
                FMA4(acc[j], s, wv);
            }
        }
    }

    // restage chunk 1: Hc quads 8..15 (same L2 lines as row, fetched once)
    #pragma unroll
    for (int q = 0; q < 8; ++q) myscr[q ^ sw] = src[8 + q];

    // chunk 1: k4 = 8..15 (W3 rows 96..127, ascending)
    #pragma unroll 1
    for (int k4 = 8; k4 < 16; ++k4) {
        const float4 hv = myscr[(k4 - 8) ^ sw];
        #pragma unroll
        for (int i = 0; i < 4; ++i) {
            const float s = ELEM(hv, i);
            const float* w = W3b + (size_t)(k4 * 4 + i) * 64;
            #pragma unroll
            for (int j = 0; j < 16; ++j) {
                float4 wv = *(const float4*)(w + 4 * j);
                FMA4(acc[j], s, wv);
            }
        }
    }

    // + b3, relu (j ascending)
    #pragma unroll
    for (int j = 0; j < 16; ++j) {
        float4 bv = *(const float4*)(b3 + 4 * j);
        acc[j].x = fmaxf(acc[j].x + bv.x, 0.f);
        acc[j].y = fmaxf(acc[j].y + bv.y, 0.f);
        acc[j].z = fmaxf(acc[j].z + bv.z, 0.f);
        acc[j].w = fmaxf(acc[j].w + bv.w, 0.f);
    }

    // logits = (hid @ W4) + b4, j ascending
    float lg[NUM_REL];
    #pragma unroll
    for (int j = 0; j < NUM_REL; ++j) lg[j] = 0.0f;
    #pragma unroll
    for (int jq = 0; jq < 16; ++jq) {
        #pragma unroll
        for (int i = 0; i < 4; ++i) {
            const float s = ELEM(acc[jq], i);
            const float* w = W4 + (size_t)(jq * 4 + i) * NUM_REL;
            #pragma unroll
            for (int j = 0; j < NUM_REL; ++j) lg[j] = fmaf(s, w[j], lg[j]);
        }
    }

    if (!valid) return;

    #pragma unroll
    for (int j = 0; j < NUM_REL; ++j) lg[j] += b4[j];

    // argmax, first occurrence
    int best = 0;
    float bm = lg[0];
    #pragma unroll
    for (int j = 1; j < NUM_REL; ++j)
        if (lg[j] > bm) { bm = lg[j]; best = j; }

    // softmax fp32
    float p[NUM_REL];
    float sum = 0.0f;
    #pragma unroll
    for (int j = 0; j < NUM_REL; ++j) {
        p[j] = expf(lg[j] - bm);
        sum += p[j];
    }
    float inv = 1.0f / sum;

    out_type[e] = (float)best;
    float* op = out_probs + (size_t)e * NUM_REL;
    #pragma unroll
    for (int j = 0; j < NUM_REL; ++j) op[j] = p[j] * inv;
}

extern "C" void kernel_launch(void* const* d_in, const int* in_sizes, int n_in,
                              void* d_out, int out_size, void* d_ws, size_t ws_size,
                              hipStream_t stream)
{
    const float* x  = (const float*)d_in[0];
    const int*   ei = (const int*)d_in[1];
    const float* W1 = (const float*)d_in[2];
    const float* b1 = (const float*)d_in[3];
    const float* W2 = (const float*)d_in[4];
    const float* b2 = (const float*)d_in[5];
    const float* W3 = (const float*)d_in[6];
    const float* b3 = (const float*)d_in[7];
    const float* W4 = (const float*)d_in[8];
    const float* b4 = (const float*)d_in[9];

    int N = in_sizes[0] / NODE_DIM;   // 100000
    int E = in_sizes[1] / 2;          // 1600000

    // ws: H [N*64] f32 | A [N*64] f32   (51.2 MB total)
    float* H = (float*)d_ws;
    float* A = H + (size_t)N * 64;

    int nb = (N + 255) / 256;
    int eb = (E + 255) / 256;

    float* out_type  = (float*)d_out;
    float* out_probs = (float*)d_out + E;

    hipLaunchKernelGGL(node_kernel, dim3(nb), dim3(256), 0, stream,
                       x, W1, b1, W2, b2, W3, H, A, N);
    hipLaunchKernelGGL(edge_kernel, dim3(eb), dim3(256), 0, stream,
                       ei, H, A, W3, b3, W4, b4, out_type, out_probs, E);
}